// Round 3
// baseline (549.436 us; speedup 1.0000x reference)
//
#include <hip/hip_runtime.h>

// GGNN on MI355X.
// Pipeline: [precompute_swt -> big_mm -> gating] x2; step-2 gating fuses the
// output head. All heavy math in bf16 MFMA (16x16x32), accumulate f32.
// A (256 MB f32) is the dominant HBM stream, read once per propagate step.
// R2: big_mm K-split x2 (2 waves/SIMD instead of 1), gating col-split x4.
// R3: fix nontemporal load (needs ext_vector_type, not HIP float4).

typedef float  f32x4_t  __attribute__((ext_vector_type(4)));
typedef __bf16 bf16x8_t __attribute__((ext_vector_type(8)));
typedef __bf16 bf16x4_t __attribute__((ext_vector_type(4)));

#define MFMA16(a, b, c) __builtin_amdgcn_mfma_f32_16x16x32_bf16((a), (b), (c), 0, 0, 0)

static constexpr int kB  = 8;
static constexpr int kN  = 1000;
static constexpr int kD  = 64;
static constexpr int kAD = 32;
static constexpr int kNE = 4000;          // N*E
static constexpr int kBN = 8000;          // B*N (total rows)
static constexpr int kP  = kBN * kD;      // floats per partial buffer (512000)

__device__ __forceinline__ float4 ld4(const float* p) {
    return *reinterpret_cast<const float4*>(p);
}

__device__ __forceinline__ float4 ldnt4(const float* p) {
    const f32x4_t v = __builtin_nontemporal_load(reinterpret_cast<const f32x4_t*>(p));
    return make_float4(v.x, v.y, v.z, v.w);
}

__device__ __forceinline__ bf16x8_t cvt8(float4 a, float4 b) {
    bf16x8_t r;
    r[0] = (__bf16)a.x; r[1] = (__bf16)a.y; r[2] = (__bf16)a.z; r[3] = (__bf16)a.w;
    r[4] = (__bf16)b.x; r[5] = (__bf16)b.y; r[6] = (__bf16)b.z; r[7] = (__bf16)b.w;
    return r;
}

// bf16x8 of (p0[i] + p1[i]) for i in 0..7 — partial-sum merge
__device__ __forceinline__ bf16x8_t sum8(const float* p0, const float* p1) {
    const float4 a0 = ld4(p0), a1 = ld4(p0 + 4);
    const float4 b0 = ld4(p1), b1 = ld4(p1 + 4);
    bf16x8_t r;
    r[0] = (__bf16)(a0.x + b0.x); r[1] = (__bf16)(a0.y + b0.y);
    r[2] = (__bf16)(a0.z + b0.z); r[3] = (__bf16)(a0.w + b0.w);
    r[4] = (__bf16)(a1.x + b1.x); r[5] = (__bf16)(a1.y + b1.y);
    r[6] = (__bf16)(a1.z + b1.z); r[7] = (__bf16)(a1.w + b1.w);
    return r;
}

__device__ __forceinline__ float sigm(float x) {
    x = fminf(fmaxf(x, -30.f), 30.f);
    return 1.0f / (1.0f + __expf(-x));
}

__device__ __forceinline__ float fast_tanh(float x) {
    x = fminf(fmaxf(x, -15.f), 15.f);
    const float e = __expf(-2.0f * x);
    return (1.0f - e) / (1.0f + e);
}

// ---------------------------------------------------------------------------
// SWT[(b*2+h)*64 + f][j] (bf16, j = e*1000 + jj, row stride kNE) =
//   sum_d state[b][jj][d] * W[e][f][d]   with W = (h ? W_out : W_in)
// grid: 1024 = 16 jt x 4 e x 2 h x 8 b, block 256 (4 waves, 16 j-rows each).
// ---------------------------------------------------------------------------
__global__ __launch_bounds__(256) void precompute_swt(
    const float* __restrict__ state,   // [8000][64]
    const float* __restrict__ W_in,    // [4][64][64]
    const float* __restrict__ W_out,
    __bf16* __restrict__ SWT)
{
    const int bx = blockIdx.x;
    const int jt = bx & 15;
    const int e  = (bx >> 4) & 3;
    const int h  = (bx >> 6) & 1;
    const int b  = bx >> 7;
    const float* W = (h ? W_out : W_in) + e * kD * kD;

    const int tid  = threadIdx.x;
    const int w    = tid >> 6;
    const int lane = tid & 63;
    const int m    = lane & 15;
    const int q    = lane >> 4;

    __shared__ __bf16 T[64][72];  // [f][j_local], +8 pad vs bank conflicts

    const int  jj    = jt * 64 + w * 16 + m;
    const bool valid = (jj < kN);
    const float* srow = state + ((size_t)b * kN + (valid ? jj : kN - 1)) * kD + q * 8;
    float4 a0 = ld4(srow),      a1 = ld4(srow + 4);
    float4 a2 = ld4(srow + 32), a3 = ld4(srow + 36);
    if (!valid) {
        a0 = make_float4(0.f, 0.f, 0.f, 0.f); a1 = a0; a2 = a0; a3 = a0;
    }
    const bf16x8_t af0 = cvt8(a0, a1);
    const bf16x8_t af1 = cvt8(a2, a3);

    #pragma unroll
    for (int c = 0; c < 4; ++c) {
        const int f = c * 16 + m;
        const float* wrow = W + f * kD + q * 8;
        const bf16x8_t bf0 = cvt8(ld4(wrow),      ld4(wrow + 4));
        const bf16x8_t bf1 = cvt8(ld4(wrow + 32), ld4(wrow + 36));
        f32x4_t acc = {0.f, 0.f, 0.f, 0.f};
        acc = MFMA16(af0, bf0, acc);
        acc = MFMA16(af1, bf1, acc);
        const int j0 = w * 16 + q * 4;
        bf16x4_t v;
        v[0] = (__bf16)acc[0]; v[1] = (__bf16)acc[1];
        v[2] = (__bf16)acc[2]; v[3] = (__bf16)acc[3];
        *reinterpret_cast<bf16x4_t*>(&T[f][j0]) = v;
    }
    __syncthreads();

    const size_t rowbase = (size_t)((b * 2 + h) * kD);
    #pragma unroll
    for (int rep = 0; rep < 2; ++rep) {
        const int cc = tid + rep * 256;       // 0..511
        const int f  = cc >> 3;
        const int ch = cc & 7;
        const int jj0 = jt * 64 + ch * 8;
        if (jj0 < kN) {
            const uint4 v = *reinterpret_cast<uint4*>(&T[f][ch * 8]);
            *reinterpret_cast<uint4*>(SWT + (rowbase + f) * kNE + e * kN + jj0) = v;
        }
    }
}

// ---------------------------------------------------------------------------
// a_half_p[ks][b][i][f] = sum_{j in Kslice(ks)} A[b][i][h*4000+j] * SWT[...][j]
// grid: 512 = 16 tiles x 2 h x 8 b x 2 ks; block 256 (4 waves x 16 rows).
// 2 blocks/CU -> 2 waves/SIMD; barrier-free K-loop, depth-1 reg prefetch.
// ks=0 covers k in [0,1984) (31 x 64); ks=1 covers [1984,4000) (31 x 64 + 32).
// ---------------------------------------------------------------------------
__global__ __launch_bounds__(256, 2) void big_mm(
    const float* __restrict__ A,        // [8][1000][8000]
    const __bf16* __restrict__ SWT,     // [16*64][4000]
    float* __restrict__ a_in_p,         // [2][8000][64]
    float* __restrict__ a_out_p)
{
    const int bx   = blockIdx.x;
    const int tile = bx & 15;
    const int h    = (bx >> 4) & 1;
    const int b    = (bx >> 5) & 7;
    const int ks   = (bx >> 8) & 1;
    const int tid  = threadIdx.x;
    const int w    = tid >> 6;
    const int lane = tid & 63;
    const int m    = lane & 15;
    const int q    = lane >> 4;

    const int row  = tile * 64 + w * 16 + m;
    const int rowc = row < kN ? row : kN - 1;
    const int kbeg = ks * 1984;

    const float*  Ap = A + ((size_t)b * kN + rowc) * (2 * kNE) + h * kNE + kbeg + q * 8;
    const __bf16* SW = SWT + ((size_t)(b * 2 + h) * kD) * kNE + kbeg + q * 8;
    const __bf16* SB0 = SW + (size_t)(0 * 16 + m) * kNE;
    const __bf16* SB1 = SW + (size_t)(1 * 16 + m) * kNE;
    const __bf16* SB2 = SW + (size_t)(2 * 16 + m) * kNE;
    const __bf16* SB3 = SW + (size_t)(3 * 16 + m) * kNE;

    f32x4_t acc0 = {0.f, 0.f, 0.f, 0.f};
    f32x4_t acc1 = {0.f, 0.f, 0.f, 0.f};
    f32x4_t acc2 = {0.f, 0.f, 0.f, 0.f};
    f32x4_t acc3 = {0.f, 0.f, 0.f, 0.f};

    // prologue: relative k = 0 (both 32-halves)
    bf16x8_t ca0 = cvt8(ldnt4(Ap + 0),  ldnt4(Ap + 4));
    bf16x8_t ca1 = cvt8(ldnt4(Ap + 32), ldnt4(Ap + 36));
    bf16x8_t cb00 = *(const bf16x8_t*)(SB0);
    bf16x8_t cb01 = *(const bf16x8_t*)(SB1);
    bf16x8_t cb02 = *(const bf16x8_t*)(SB2);
    bf16x8_t cb03 = *(const bf16x8_t*)(SB3);
    bf16x8_t cb10 = *(const bf16x8_t*)(SB0 + 32);
    bf16x8_t cb11 = *(const bf16x8_t*)(SB1 + 32);
    bf16x8_t cb12 = *(const bf16x8_t*)(SB2 + 32);
    bf16x8_t cb13 = *(const bf16x8_t*)(SB3 + 32);

    // 31 full 64-wide iterations; ks=1 adds a 32-wide tail afterwards.
    for (int kk = 0; kk < 31; ++kk) {
        const int kn = (kk + 1) * 64;
        // last iteration's 2nd-half prefetch redirected to 0 (valid, unused)
        const int k2 = (kk < 30) ? (kn + 32) : 0;

        const float4 x0 = ldnt4(Ap + kn),  x1 = ldnt4(Ap + kn + 4);
        const float4 x2 = ldnt4(Ap + k2),  x3 = ldnt4(Ap + k2 + 4);
        const bf16x8_t nb00 = *(const bf16x8_t*)(SB0 + kn);
        const bf16x8_t nb01 = *(const bf16x8_t*)(SB1 + kn);
        const bf16x8_t nb02 = *(const bf16x8_t*)(SB2 + kn);
        const bf16x8_t nb03 = *(const bf16x8_t*)(SB3 + kn);
        const bf16x8_t nb10 = *(const bf16x8_t*)(SB0 + k2);
        const bf16x8_t nb11 = *(const bf16x8_t*)(SB1 + k2);
        const bf16x8_t nb12 = *(const bf16x8_t*)(SB2 + k2);
        const bf16x8_t nb13 = *(const bf16x8_t*)(SB3 + k2);

        acc0 = MFMA16(ca0, cb00, acc0);
        acc1 = MFMA16(ca0, cb01, acc1);
        acc2 = MFMA16(ca0, cb02, acc2);
        acc3 = MFMA16(ca0, cb03, acc3);
        acc0 = MFMA16(ca1, cb10, acc0);
        acc1 = MFMA16(ca1, cb11, acc1);
        acc2 = MFMA16(ca1, cb12, acc2);
        acc3 = MFMA16(ca1, cb13, acc3);

        ca0 = cvt8(x0, x1);
        ca1 = cvt8(x2, x3);
        cb00 = nb00; cb01 = nb01; cb02 = nb02; cb03 = nb03;
        cb10 = nb10; cb11 = nb11; cb12 = nb12; cb13 = nb13;
    }
    if (ks == 1) {  // tail: k = 1984 + 1984 = 3968, 32 wide (first half only)
        acc0 = MFMA16(ca0, cb00, acc0);
        acc1 = MFMA16(ca0, cb01, acc1);
        acc2 = MFMA16(ca0, cb02, acc2);
        acc3 = MFMA16(ca0, cb03, acc3);
    }

    float* dst = (h ? a_out_p : a_in_p) + (size_t)ks * kP + (size_t)b * kN * kD;
    const int i0 = tile * 64 + w * 16 + q * 4;
    #pragma unroll
    for (int r = 0; r < 4; ++r) {
        const int i = i0 + r;
        if (i < kN) {
            float* drow = dst + (size_t)i * kD + m;
            drow[0]  = acc0[r];
            drow[16] = acc1[r];
            drow[32] = acc2[r];
            drow[48] = acc3[r];
        }
    }
}

// ---------------------------------------------------------------------------
// Gating, col-split: block = 256 (4 waves), 16 rows per block, wave c owns
// output cols f = c*16..c*16+15. 500 blocks -> 2000 waves (~8/CU).
//   a = [a_in | a_out | state] (K=192);  a_in/a_out = sum of 2 K-partials
//   r = sigm(a @ W_r^T); z = sigm(a @ W_z^T)
//   h = tanh([a_in|a_out] @ W_h[:,:128]^T + (r*state) @ W_h[:,128:]^T)
//   ns = (1-z)*state + z*h
// step 1: write ns. step 2: fused head out = sum_f tanh([ns|ann]@Wo1^T)_f * Wo2_f
// ---------------------------------------------------------------------------
__global__ __launch_bounds__(256, 2) void gating(
    const float* __restrict__ a_in_p,   // [2][8000][64]
    const float* __restrict__ a_out_p,
    const float* __restrict__ state,
    const float* __restrict__ W_r,
    const float* __restrict__ W_z,
    const float* __restrict__ W_h,
    float* __restrict__ s_next,
    const float* __restrict__ ann,
    const float* __restrict__ Wo1,
    const float* __restrict__ Wo2,
    float* __restrict__ out,
    const int step)
{
    const int i0   = blockIdx.x * 16;
    const int tid  = threadIdx.x;
    const int c    = tid >> 6;           // wave = column slice
    const int lane = tid & 63;
    const int m    = lane & 15;
    const int q    = lane >> 4;
    const int f    = c * 16 + m;

    __shared__ __bf16 TL[16][72];
    __shared__ float  Osum[4][16];

    const size_t rowA = (size_t)(i0 + m);

    bf16x8_t xf[6];
    {
        const float* p = a_in_p + rowA * kD + q * 8;
        xf[0] = sum8(p,      p + kP);
        xf[1] = sum8(p + 32, p + 32 + kP);
        p = a_out_p + rowA * kD + q * 8;
        xf[2] = sum8(p,      p + kP);
        xf[3] = sum8(p + 32, p + 32 + kP);
        p = state + rowA * kD + q * 8;
        xf[4] = cvt8(ld4(p),      ld4(p + 4));
        xf[5] = cvt8(ld4(p + 32), ld4(p + 36));
    }

    f32x4_t accr = {0.f, 0.f, 0.f, 0.f};
    f32x4_t accz = {0.f, 0.f, 0.f, 0.f};
    f32x4_t acch = {0.f, 0.f, 0.f, 0.f};

    const float* wr = W_r + f * 192 + q * 8;
    const float* wz = W_z + f * 192 + q * 8;
    const float* wh = W_h + f * 192 + q * 8;
    #pragma unroll
    for (int kc = 0; kc < 6; ++kc) {
        accr = MFMA16(xf[kc], cvt8(ld4(wr + kc * 32), ld4(wr + kc * 32 + 4)), accr);
        accz = MFMA16(xf[kc], cvt8(ld4(wz + kc * 32), ld4(wz + kc * 32 + 4)), accz);
        if (kc < 4)  // h-preact uses only [a_in|a_out] here (K=128)
            acch = MFMA16(xf[kc], cvt8(ld4(wh + kc * 32), ld4(wh + kc * 32 + 4)), acch);
    }

    float sC[4];
    #pragma unroll
    for (int r = 0; r < 4; ++r)
        sC[r] = state[(size_t)(i0 + q * 4 + r) * kD + f];

    // rs = sigm(r_pre) * state -> LDS transpose (C layout -> A layout)
    #pragma unroll
    for (int r = 0; r < 4; ++r)
        TL[q * 4 + r][f] = (__bf16)(sigm(accr[r]) * sC[r]);
    __syncthreads();
    const bf16x8_t rs0 = *(const bf16x8_t*)&TL[m][q * 8];
    const bf16x8_t rs1 = *(const bf16x8_t*)&TL[m][32 + q * 8];

    const float* wh3 = W_h + f * 192 + 128 + q * 8;
    acch = MFMA16(rs0, cvt8(ld4(wh3),      ld4(wh3 + 4)),  acch);
    acch = MFMA16(rs1, cvt8(ld4(wh3 + 32), ld4(wh3 + 36)), acch);

    float ns[4];
    #pragma unroll
    for (int r = 0; r < 4; ++r) {
        const float zv = sigm(accz[r]);
        ns[r] = (1.f - zv) * sC[r] + zv * fast_tanh(acch[r]);
    }

    if (step == 1) {
        #pragma unroll
        for (int r = 0; r < 4; ++r)
            s_next[(size_t)(i0 + q * 4 + r) * kD + f] = ns[r];
    } else {
        __syncthreads();  // all waves done reading rs frags from TL
        #pragma unroll
        for (int r = 0; r < 4; ++r)
            TL[q * 4 + r][f] = (__bf16)ns[r];
        __syncthreads();
        const bf16x8_t j0 = *(const bf16x8_t*)&TL[m][q * 8];
        const bf16x8_t j1 = *(const bf16x8_t*)&TL[m][32 + q * 8];
        const float* ap = ann + rowA * kAD + q * 8;
        const bf16x8_t j2 = cvt8(ld4(ap), ld4(ap + 4));

        f32x4_t acco = {0.f, 0.f, 0.f, 0.f};
        const float* wo = Wo1 + (size_t)f * 96 + q * 8;
        acco = MFMA16(j0, cvt8(ld4(wo),      ld4(wo + 4)),  acco);
        acco = MFMA16(j1, cvt8(ld4(wo + 32), ld4(wo + 36)), acco);
        acco = MFMA16(j2, cvt8(ld4(wo + 64), ld4(wo + 68)), acco);

        const float w2 = Wo2[f];
        float vs[4];
        #pragma unroll
        for (int r = 0; r < 4; ++r)
            vs[r] = fast_tanh(acco[r]) * w2;
        #pragma unroll
        for (int off = 1; off <= 8; off <<= 1) {
            #pragma unroll
            for (int r = 0; r < 4; ++r)
                vs[r] += __shfl_xor(vs[r], off, 64);
        }
        if (m == 0) {
            #pragma unroll
            for (int r = 0; r < 4; ++r)
                Osum[c][q * 4 + r] = vs[r];
        }
        __syncthreads();
        if (tid < 16)
            out[i0 + tid] = Osum[0][tid] + Osum[1][tid] + Osum[2][tid] + Osum[3][tid];
    }
}

extern "C" void kernel_launch(void* const* d_in, const int* in_sizes, int n_in,
                              void* d_out, int out_size, void* d_ws, size_t ws_size,
                              hipStream_t stream) {
    (void)in_sizes; (void)n_in; (void)out_size; (void)ws_size;

    const float* prop_state = (const float*)d_in[0];
    const float* annotation = (const float*)d_in[1];
    const float* A          = (const float*)d_in[2];
    const float* W_in       = (const float*)d_in[3];
    const float* W_out      = (const float*)d_in[4];
    const float* W_r        = (const float*)d_in[5];
    const float* W_z        = (const float*)d_in[6];
    const float* W_h        = (const float*)d_in[7];
    const float* Wo1        = (const float*)d_in[8];
    const float* Wo2        = (const float*)d_in[9];
    float* out = (float*)d_out;

    char* ws = (char*)d_ws;
    __bf16* SWT    = (__bf16*)(ws);                 // 8,192,000 B
    float*  a_in_p = (float*)(ws + 8192000);        // 2 x 2,048,000 B
    float*  a_out_p= (float*)(ws + 12288000);       // 2 x 2,048,000 B
    float*  s1     = (float*)(ws + 16384000);       // 2,048,000 B (tot 18.4 MB)

    // step 1
    precompute_swt<<<1024, 256, 0, stream>>>(prop_state, W_in, W_out, SWT);
    big_mm<<<512, 256, 0, stream>>>(A, SWT, a_in_p, a_out_p);
    gating<<<500, 256, 0, stream>>>(a_in_p, a_out_p, prop_state, W_r, W_z, W_h,
                                    s1, nullptr, nullptr, nullptr, nullptr, 1);
    // step 2 (+ fused output head)
    precompute_swt<<<1024, 256, 0, stream>>>(s1, W_in, W_out, SWT);
    big_mm<<<512, 256, 0, stream>>>(A, SWT, a_in_p, a_out_p);
    gating<<<500, 256, 0, stream>>>(a_in_p, a_out_p, s1, W_r, W_z, W_h,
                                    nullptr, annotation, Wo1, Wo2, out, 2);
}